// Round 16
// baseline (63.621 us; speedup 1.0000x reference)
//
#include <hip/hip_runtime.h>
#include <hip/hip_bf16.h>
#include <math.h>

// Steerable CNP target prediction — separable RBF + bf16 MFMA, SINGLE kernel.
//
// out[t,c] = (sum_i Kx[t,i] * V[t,c,i]) / (Sx[t]*Sy[t]),
//   V[t,c,i] = sum_j Ky[t,j] * FMc[j,i]   <- GEMM: mfma_f32_16x16x32_bf16
//
// Round 16 = r15 structure (15.05us) with the pack kernel FUSED in via a
// grid-wide producer/consumer gate: each block packs 1/256th of bfB (wave 0,
// one float4/lane), then arrive/depart monotonic counters in ws gate the
// B-fragment reads. The spin overlaps tile-0's exp phase; its barrier is
// the existing phase-0 barrier. Counters stay equal at every kernel entry
// (arrive +nblk, depart +nblk per launch) -> poison-agnostic, deterministic
// across graph replays. All 256 blocks are co-resident (21KB LDS, ~112
// VGPR -> >=2 blocks/CU capacity) so the spin cannot deadlock.
// Lessons kept: named regs (r1), no forced occ (r3), VGPR<128 (r4), packed
// coalesced B (r10), prefetch early (r11), no tables (r12), no serial prep
// blocks (r14), B-reg reuse across 2 tiles (r15).

#define NA      128
#define TT      16
#define TILES   2
#define THREADS 512

typedef __attribute__((ext_vector_type(8))) short short8;
typedef __attribute__((ext_vector_type(4))) float f32x4;

__device__ __forceinline__ short f2bf(float x) {
    __hip_bfloat16 h = __float2bfloat16(x);
    return *reinterpret_cast<short*>(&h);
}

__global__ __launch_bounds__(THREADS)
void cnp_fused(const float* __restrict__ fm,    // [4][NA][NA]
               const float* __restrict__ grid,  // [NA*NA][2]
               const float* __restrict__ xt,    // [T][2]
               const float* __restrict__ lsp,   // [1]
               short* __restrict__ bfB,         // ws: [4][8][4][64][8] bf16
               unsigned* __restrict__ syncc,    // ws: {arrive, depart}
               float* __restrict__ out,         // means [T][2] then sigmas [T][2]
               int n_target)
{
    __shared__ __attribute__((aligned(16))) float Kx[TT * NA];      // 8 KB
    __shared__ __attribute__((aligned(16))) float Ky32[TT * NA];    // 8 KB
    __shared__ __attribute__((aligned(16))) short kyA[4 * 64 * 8];  // 4 KB
    __shared__ float psx[TT], psy[TT];
    __shared__ float red[4][2][TT];

    const int tid   = threadIdx.x;
    const int wid   = tid >> 6;
    const int c     = wid & 3;        // channel
    const int nh    = wid >> 2;       // n-half
    const int lane  = tid & 63;
    const int tbase = blockIdx.x * (TT * TILES);
    const int nblk  = gridDim.x;

    const float l      = lsp[0];
    const float inv2l2 = 0.5f / (l * l);

    // ---- producer: pack this block's 1/nblk share of bfB (wave 0 only) ----
    // bfB[(((c*8+n)*4+s)*64+L)*8+e] = FMc[k][i], k=s*32+((L>>4)&3)*8+e,
    // i=n*16+(L&15); softplus on c>=2.
    if (tid < 64) {
        for (int idx = blockIdx.x * 64 + tid; idx < 16384; idx += nblk * 64) {
            const int cc = idx >> 12;
            const int k  = (idx >> 5) & 127;
            const int i0 = (idx & 31) * 4;
            float4 v = *reinterpret_cast<const float4*>(fm + cc * NA * NA + k * NA + i0);
            if (cc >= 2) {
                v.x = (v.x > 15.0f) ? v.x : log1pf(__expf(v.x));
                v.y = (v.y > 15.0f) ? v.y : log1pf(__expf(v.y));
                v.z = (v.z > 15.0f) ? v.z : log1pf(__expf(v.z));
                v.w = (v.w > 15.0f) ? v.w : log1pf(__expf(v.w));
            }
            const int s  = k >> 5;
            const int e  = k & 7;
            const int Lk = ((k >> 3) & 3) * 16;
            const float vv[4] = {v.x, v.y, v.z, v.w};
#pragma unroll
            for (int d = 0; d < 4; ++d) {
                const int i = i0 + d;
                const int n = i >> 4;
                const int L = Lk + (i & 15);
                bfB[(((cc * 8 + n) * 4 + s) * 64 + L) * 8 + e] = f2bf(vv[d]);
            }
        }
    }
    // arrive: release-add on A (waits wave-0's pack stores, device scope).
    // d0 snapshot of D happens before our arrive -> before any gate opens
    // -> before any depart of this launch -> d0 == launch-entry value.
    unsigned gate_target = 0;
    if (tid == 0) {
        const unsigned d0 = __hip_atomic_load(&syncc[1], __ATOMIC_RELAXED,
                                              __HIP_MEMORY_SCOPE_AGENT);
        __hip_atomic_fetch_add(&syncc[0], 1u, __ATOMIC_RELEASE,
                               __HIP_MEMORY_SCOPE_AGENT);
        gate_target = d0 + (unsigned)nblk;
    }

    const int icol = lane & 15;
    const int tb   = (lane >> 4) * 4;
    short8 b00, b01, b02, b03, b10, b11, b12, b13;
    short8 b20, b21, b22, b23, b30, b31, b32, b33;

    for (int tt = 0; tt < TILES; ++tt) {
        const int t0 = tbase + tt * TT;

        // ---- phase 0: exps -> LDS (Kx fp32, Ky fp32 + bf16 A-frag) ----
        // grid[g] = (ax[g>>7], ax[g&127])  =>  ax[j] = grid[j*2+1]
#pragma unroll
        for (int s = 0; s < 4; ++s) {
            const int k = s * THREADS + tid;   // 0..2047
            const int t = k >> 7;
            const int j = k & 127;
            int tg = t0 + t; if (tg >= n_target) tg = n_target - 1;
            const float ax = grid[j * 2 + 1];
            const float dx = xt[tg * 2 + 0] - ax;
            const float dy = xt[tg * 2 + 1] - ax;
            const float kxv = __expf(-dx * dx * inv2l2);
            const float kyv = __expf(-dy * dy * inv2l2);
            Kx[t * NA + j]   = kxv;
            Ky32[t * NA + j] = kyv;
            const int ss = j >> 5, g = (j & 31) >> 3, e = j & 7;
            kyA[((ss * 64) + g * 16 + (t & 15)) * 8 + e] = f2bf(kyv);
        }

        // ---- gate (tile 0 only): spin until all blocks packed ----
        if (tt == 0 && tid == 0) {
            while (__hip_atomic_load(&syncc[0], __ATOMIC_RELAXED,
                                     __HIP_MEMORY_SCOPE_AGENT) < gate_target)
                __builtin_amdgcn_s_sleep(2);
        }
        __syncthreads();   // phase-0 barrier; for tt==0 also releases the gate

        if (tt == 0) {
            __threadfence();   // acquire: drop stale bfB lines before 1st read
            const short8* bbase = reinterpret_cast<const short8*>(bfB)
                                + c * 2048 + nh * 1024 + lane;
            b00 = bbase[0];         b01 = bbase[64];
            b02 = bbase[128];       b03 = bbase[192];
            b10 = bbase[256];       b11 = bbase[256 + 64];
            b12 = bbase[256 + 128]; b13 = bbase[256 + 192];
            b20 = bbase[512];       b21 = bbase[512 + 64];
            b22 = bbase[512 + 128]; b23 = bbase[512 + 192];
            b30 = bbase[768];       b31 = bbase[768 + 64];
            b32 = bbase[768 + 128]; b33 = bbase[768 + 192];
            if (tid == 0)          // depart: restores A==D for next launch
                __hip_atomic_fetch_add(&syncc[1], 1u, __ATOMIC_RELAXED,
                                       __HIP_MEMORY_SCOPE_AGENT);
        }

        // ---- Sx/Sy: shallow reduce, 32 groups (t x axis) x 16 lanes ----
        {
            const int grp  = tid >> 4;        // 0..31
            const int l16  = tid & 15;
            const int t    = grp >> 1;
            const int axis = grp & 1;
            const float* kb = axis ? Ky32 : Kx;
            const float4 q0 = *reinterpret_cast<const float4*>(&kb[t * NA + l16 * 8]);
            const float4 q1 = *reinterpret_cast<const float4*>(&kb[t * NA + l16 * 8 + 4]);
            float u = ((q0.x + q0.y) + (q0.z + q0.w)) + ((q1.x + q1.y) + (q1.z + q1.w));
            u += __shfl_xor(u, 1); u += __shfl_xor(u, 2);
            u += __shfl_xor(u, 4); u += __shfl_xor(u, 8);
            if (l16 == 0) { if (axis) psy[t] = u; else psx[t] = u; }
        }

        // ---- A-frags ----
        const short8* kap = reinterpret_cast<const short8*>(kyA);
        const short8 a0 = kap[0 * 64 + lane];
        const short8 a1 = kap[1 * 64 + lane];
        const short8 a2 = kap[2 * 64 + lane];
        const short8 a3 = kap[3 * 64 + lane];

        // ---- MFMA + stage-2 dot ----
        f32x4 p = {0.f, 0.f, 0.f, 0.f};
#define NTILE(NN, B0, B1, B2, B3)                                              \
        {                                                                      \
            f32x4 acc = {0.f, 0.f, 0.f, 0.f};                                  \
            acc = __builtin_amdgcn_mfma_f32_16x16x32_bf16(a0, B0, acc, 0, 0, 0); \
            acc = __builtin_amdgcn_mfma_f32_16x16x32_bf16(a1, B1, acc, 0, 0, 0); \
            acc = __builtin_amdgcn_mfma_f32_16x16x32_bf16(a2, B2, acc, 0, 0, 0); \
            acc = __builtin_amdgcn_mfma_f32_16x16x32_bf16(a3, B3, acc, 0, 0, 0); \
            const int i = (nh * 4 + (NN)) * 16 + icol;                         \
            p.x = fmaf(Kx[(tb + 0) * NA + i], acc.x, p.x);                     \
            p.y = fmaf(Kx[(tb + 1) * NA + i], acc.y, p.y);                     \
            p.z = fmaf(Kx[(tb + 2) * NA + i], acc.z, p.z);                     \
            p.w = fmaf(Kx[(tb + 3) * NA + i], acc.w, p.w);                     \
        }
        NTILE(0, b00, b01, b02, b03)
        NTILE(1, b10, b11, b12, b13)
        NTILE(2, b20, b21, b22, b23)
        NTILE(3, b30, b31, b32, b33)
#undef NTILE

        // ---- reduce numer over the 16 i-lanes (strides 1,2,4,8) ----
#pragma unroll
        for (int st = 1; st <= 8; st <<= 1) {
            p.x += __shfl_xor(p.x, st);
            p.y += __shfl_xor(p.y, st);
            p.z += __shfl_xor(p.z, st);
            p.w += __shfl_xor(p.w, st);
        }
        if (icol == 0) {
            red[c][nh][tb + 0] = p.x;
            red[c][nh][tb + 1] = p.y;
            red[c][nh][tb + 2] = p.z;
            red[c][nh][tb + 3] = p.w;
        }
        __syncthreads();

        // ---- epilogue: combine n-halves, normalize, write (64 outputs) ----
        if (tid < 4 * TT) {
            const int t  = tid & (TT - 1);
            const int cc = tid >> 4;            // requires TT == 16
            const int tg = t0 + t;
            if (tg < n_target) {
                const float numer = red[cc][0][t] + red[cc][1][t];
                const float val = numer / (psx[t] * psy[t]);
                if (cc < 2) out[tg * 2 + cc] = val;                      // means
                else        out[n_target * 2 + tg * 2 + (cc - 2)] = val; // sigmas
            }
        }
    }
}

extern "C" void kernel_launch(void* const* d_in, const int* in_sizes, int n_in,
                              void* d_out, int out_size, void* d_ws, size_t ws_size,
                              hipStream_t stream) {
    const float* fm   = (const float*)d_in[0];
    const float* grid = (const float*)d_in[1];
    const float* xt   = (const float*)d_in[2];
    const float* lsp  = (const float*)d_in[3];
    float* out = (float*)d_out;

    char* w = (char*)d_ws;
    short* bfB      = (short*)w;               // 128 KB packed B
    unsigned* syncc = (unsigned*)(w + 131072); // {arrive, depart}, poison-safe

    const int n_target = in_sizes[2] / 2;                            // 8192
    const int blocks = (n_target + TT * TILES - 1) / (TT * TILES);   // 256

    hipLaunchKernelGGL(cnp_fused, dim3(blocks), dim3(THREADS), 0, stream,
                       fm, grid, xt, lsp, bfB, syncc, out, n_target);
}

// Round 17
// 41.184 us; speedup vs baseline: 1.5448x; 1.5448x over previous
//
#include <hip/hip_runtime.h>
#include <hip/hip_bf16.h>
#include <math.h>

// Steerable CNP target prediction — separable RBF + bf16 MFMA, ONE dispatch.
//
// out[t,c] = (sum_i Kx[t,i] * V[t,c,i]) / (Sx[t]*Sy[t]),
//   V[t,c,i] = sum_j Ky[t,j] * FMc[j,i]   <- GEMM: mfma_f32_16x16x32_bf16
//
// Round 17: gateless fusion. Each block packs its OWN B-fragments through an
// LDS transpose (4 chunks x 64KB: coalesced float4 staging with XOR swizzle
// i ^= (kk>>3)<<3 -> frag reads <=2-way bank-aliased = free), softplus inline
// (wave-uniform per unrolled q). No ws, no atomics, no fences (r16 lesson:
// device-scope gates/fences cost 4x). Tile phase identical to r15 (15.05us).
// Lessons: named regs (r1), no forced occ (r3), VGPR<128 (r4), coalesced
// pack (r10), prefetch/overlap (r11), no tables (r12), no serial prep (r14),
// B-reg reuse across 2 tiles (r15), no cross-block deps (r16).

#define NA      128
#define TT      16
#define TILES   2
#define THREADS 512

typedef __attribute__((ext_vector_type(8))) short short8;
typedef __attribute__((ext_vector_type(4))) float f32x4;

__device__ __forceinline__ short f2bf(float x) {
    __hip_bfloat16 h = __float2bfloat16(x);
    return *reinterpret_cast<short*>(&h);
}

__global__ __launch_bounds__(THREADS)
void cnp_one(const float* __restrict__ fm,    // [4][NA][NA]
             const float* __restrict__ grid,  // [NA*NA][2]
             const float* __restrict__ xt,    // [T][2]
             const float* __restrict__ lsp,   // [1]
             float* __restrict__ out,         // means [T][2] then sigmas [T][2]
             int n_target)
{
    __shared__ __attribute__((aligned(16))) float fmS[4 * 32 * NA];  // 64 KB
    __shared__ __attribute__((aligned(16))) float Kx[TT * NA];       // 8 KB
    __shared__ __attribute__((aligned(16))) float Ky32[TT * NA];     // 8 KB
    __shared__ __attribute__((aligned(16))) short kyA[4 * 64 * 8];   // 4 KB
    __shared__ float psx[TT], psy[TT];
    __shared__ float red[4][2][TT];

    const int tid   = threadIdx.x;
    const int wid   = tid >> 6;
    const int c     = wid & 3;        // channel
    const int nh    = wid >> 2;       // n-half
    const int lane  = tid & 63;
    const int g     = lane >> 4;      // frag row-group
    const int m     = lane & 15;      // frag m / i-col
    const int tbase = blockIdx.x * (TT * TILES);

    const float l      = lsp[0];
    const float inv2l2 = 0.5f / (l * l);

    // ================= phase A: per-block B-frag pack via LDS =================
    // B-frag def (as r15's bfB): lane L of wave (c, n=nh*4+nn), chunk s holds
    // FMc[k][i], k = s*32 + g*8 + e, i = n*16 + m  (softplus on c>=2).
    // Staging layout: fmS[(cc*32+kk)*NA + (i ^ ((kk>>3)<<3))]  (bank swizzle).
    short8 b00, b01, b02, b03, b10, b11, b12, b13;
    short8 b20, b21, b22, b23, b30, b31, b32, b33;

#define SP1(z) z = ((z) > 15.0f) ? (z) : log1pf(__expf(z))
#define STAGE(S)                                                               \
    _Pragma("unroll")                                                          \
    for (int q = 0; q < 8; ++q) {                                              \
        const int f4  = q * 512 + tid;                                         \
        const int cc  = f4 >> 10;        /* uniform per q: cc = q>>1 */        \
        const int rem = f4 & 1023;                                             \
        const int kk  = rem >> 5;                                              \
        const int i4  = (rem & 31) << 2;                                       \
        float4 v = *reinterpret_cast<const float4*>(                           \
            fm + cc * (NA * NA) + ((S) * 32 + kk) * NA + i4);                  \
        if (q >= 4) { SP1(v.x); SP1(v.y); SP1(v.z); SP1(v.w); }                \
        *reinterpret_cast<float4*>(                                            \
            &fmS[(cc * 32 + kk) * NA + (i4 ^ ((kk >> 3) << 3))]) = v;          \
    }

#define FRAG(BN, NN)                                                           \
    {                                                                          \
        const int ibase = (((nh * 4 + (NN)) * 16 + m) ^ (g << 3));             \
        const float* rp = &fmS[(c * 32 + g * 8) * NA + ibase];                 \
        short8 bv;                                                             \
        bv[0] = f2bf(rp[0 * NA]); bv[1] = f2bf(rp[1 * NA]);                    \
        bv[2] = f2bf(rp[2 * NA]); bv[3] = f2bf(rp[3 * NA]);                    \
        bv[4] = f2bf(rp[4 * NA]); bv[5] = f2bf(rp[5 * NA]);                    \
        bv[6] = f2bf(rp[6 * NA]); bv[7] = f2bf(rp[7 * NA]);                    \
        BN = bv;                                                               \
    }

#define CHUNK(S, BA, BB, BC, BD)                                               \
    STAGE(S)                                                                   \
    __syncthreads();                                                           \
    FRAG(BA, 0) FRAG(BB, 1) FRAG(BC, 2) FRAG(BD, 3)                            \
    __syncthreads();

    CHUNK(0, b00, b10, b20, b30)
    CHUNK(1, b01, b11, b21, b31)
    CHUNK(2, b02, b12, b22, b32)
    CHUNK(3, b03, b13, b23, b33)
#undef CHUNK
#undef FRAG
#undef STAGE
#undef SP1

    // ================= phase B: two 16-target tiles (as r15) =================
    const int icol = m;
    const int tb   = g * 4;

    for (int tt = 0; tt < TILES; ++tt) {
        const int t0 = tbase + tt * TT;

        // ---- exps -> LDS (Kx fp32, Ky fp32 + bf16 A-frag) ----
        // grid[gg] = (ax[gg>>7], ax[gg&127])  =>  ax[j] = grid[j*2+1]
#pragma unroll
        for (int s = 0; s < 4; ++s) {
            const int k = s * THREADS + tid;   // 0..2047
            const int t = k >> 7;
            const int j = k & 127;
            int tg = t0 + t; if (tg >= n_target) tg = n_target - 1;
            const float ax = grid[j * 2 + 1];
            const float dx = xt[tg * 2 + 0] - ax;
            const float dy = xt[tg * 2 + 1] - ax;
            const float kxv = __expf(-dx * dx * inv2l2);
            const float kyv = __expf(-dy * dy * inv2l2);
            Kx[t * NA + j]   = kxv;
            Ky32[t * NA + j] = kyv;
            const int ss = j >> 5, gg = (j & 31) >> 3, e = j & 7;
            kyA[((ss * 64) + gg * 16 + (t & 15)) * 8 + e] = f2bf(kyv);
        }
        __syncthreads();

        // ---- Sx/Sy: shallow reduce, 32 groups (t x axis) x 16 lanes ----
        {
            const int grp  = tid >> 4;        // 0..31
            const int l16  = tid & 15;
            const int t    = grp >> 1;
            const int axis = grp & 1;
            const float* kb = axis ? Ky32 : Kx;
            const float4 q0 = *reinterpret_cast<const float4*>(&kb[t * NA + l16 * 8]);
            const float4 q1 = *reinterpret_cast<const float4*>(&kb[t * NA + l16 * 8 + 4]);
            float u = ((q0.x + q0.y) + (q0.z + q0.w)) + ((q1.x + q1.y) + (q1.z + q1.w));
            u += __shfl_xor(u, 1); u += __shfl_xor(u, 2);
            u += __shfl_xor(u, 4); u += __shfl_xor(u, 8);
            if (l16 == 0) { if (axis) psy[t] = u; else psx[t] = u; }
        }

        // ---- A-frags ----
        const short8* kap = reinterpret_cast<const short8*>(kyA);
        const short8 a0 = kap[0 * 64 + lane];
        const short8 a1 = kap[1 * 64 + lane];
        const short8 a2 = kap[2 * 64 + lane];
        const short8 a3 = kap[3 * 64 + lane];

        // ---- MFMA + stage-2 dot ----
        f32x4 p = {0.f, 0.f, 0.f, 0.f};
#define NTILE(NN, B0, B1, B2, B3)                                              \
        {                                                                      \
            f32x4 acc = {0.f, 0.f, 0.f, 0.f};                                  \
            acc = __builtin_amdgcn_mfma_f32_16x16x32_bf16(a0, B0, acc, 0, 0, 0); \
            acc = __builtin_amdgcn_mfma_f32_16x16x32_bf16(a1, B1, acc, 0, 0, 0); \
            acc = __builtin_amdgcn_mfma_f32_16x16x32_bf16(a2, B2, acc, 0, 0, 0); \
            acc = __builtin_amdgcn_mfma_f32_16x16x32_bf16(a3, B3, acc, 0, 0, 0); \
            const int i = (nh * 4 + (NN)) * 16 + icol;                         \
            p.x = fmaf(Kx[(tb + 0) * NA + i], acc.x, p.x);                     \
            p.y = fmaf(Kx[(tb + 1) * NA + i], acc.y, p.y);                     \
            p.z = fmaf(Kx[(tb + 2) * NA + i], acc.z, p.z);                     \
            p.w = fmaf(Kx[(tb + 3) * NA + i], acc.w, p.w);                     \
        }
        NTILE(0, b00, b01, b02, b03)
        NTILE(1, b10, b11, b12, b13)
        NTILE(2, b20, b21, b22, b23)
        NTILE(3, b30, b31, b32, b33)
#undef NTILE

        // ---- reduce numer over the 16 i-lanes (strides 1,2,4,8) ----
#pragma unroll
        for (int st = 1; st <= 8; st <<= 1) {
            p.x += __shfl_xor(p.x, st);
            p.y += __shfl_xor(p.y, st);
            p.z += __shfl_xor(p.z, st);
            p.w += __shfl_xor(p.w, st);
        }
        if (icol == 0) {
            red[c][nh][tb + 0] = p.x;
            red[c][nh][tb + 1] = p.y;
            red[c][nh][tb + 2] = p.z;
            red[c][nh][tb + 3] = p.w;
        }
        __syncthreads();

        // ---- epilogue: combine n-halves, normalize, write (64 outputs) ----
        if (tid < 4 * TT) {
            const int t  = tid & (TT - 1);
            const int cc = tid >> 4;            // requires TT == 16
            const int tg = t0 + t;
            if (tg < n_target) {
                const float numer = red[cc][0][t] + red[cc][1][t];
                const float val = numer / (psx[t] * psy[t]);
                if (cc < 2) out[tg * 2 + cc] = val;                      // means
                else        out[n_target * 2 + tg * 2 + (cc - 2)] = val; // sigmas
            }
        }
    }
}

extern "C" void kernel_launch(void* const* d_in, const int* in_sizes, int n_in,
                              void* d_out, int out_size, void* d_ws, size_t ws_size,
                              hipStream_t stream) {
    const float* fm   = (const float*)d_in[0];
    const float* grid = (const float*)d_in[1];
    const float* xt   = (const float*)d_in[2];
    const float* lsp  = (const float*)d_in[3];
    float* out = (float*)d_out;

    const int n_target = in_sizes[2] / 2;                            // 8192
    const int blocks = (n_target + TT * TILES - 1) / (TT * TILES);   // 256

    hipLaunchKernelGGL(cnp_one, dim3(blocks), dim3(THREADS), 0, stream,
                       fm, grid, xt, lsp, out, n_target);
}

// Round 18
// 15.769 us; speedup vs baseline: 4.0345x; 2.6117x over previous
//
#include <hip/hip_runtime.h>
#include <hip/hip_bf16.h>
#include <math.h>

// Steerable CNP target prediction — separable RBF + bf16 MFMA.
// FINAL (r15 revert, session best: 15.05us, 5.7x over baseline).
//
// out[t,c] = (sum_i Kx[t,i] * V[t,c,i]) / (Sx[t]*Sy[t]),
//   V[t,c,i] = sum_j Ky[t,j] * FMc[j,i]   <- GEMM: mfma_f32_16x16x32_bf16
//
// Structure: pack_pre (128 blocks) converts FM -> softplus'd bf16 B-fragment
// layout in ws; cnp_mfma (256 blocks x 512 thr) processes 2 16-target tiles
// per block: B-frags prefetched once into 64 VGPRs, per-tile exp->LDS phase
// (Kx fp32, Ky fp32 + bf16 A-frags), shallow S-reduce, 16 MFMAs, stage-2
// Kx dot in fp32, butterfly reduce, normalized write.
// Session lessons encoded: named regs only (r1); never force occupancy (r3);
// VGPR<128 (r4); TLP/ILP don't move this op (r5-r7) — issued-work does (r8);
// coalesced packed B, never per-lane gather (r10); prefetch-before-use (r11);
// recompute cheap exps, no big tables (r12-r13); no serial prep blocks (r14);
// no cross-block gates/fences (r16); no redundant in-block pack (r17).

#define NA      128
#define TT      16
#define TILES   2
#define THREADS 512

typedef __attribute__((ext_vector_type(8))) short short8;
typedef __attribute__((ext_vector_type(4))) float f32x4;

__device__ __forceinline__ short f2bf(float x) {
    __hip_bfloat16 h = __float2bfloat16(x);
    return *reinterpret_cast<short*>(&h);
}

// ---------- pre-kernel: FM -> softplus'd bf16 fragment-linear layout ----------
// bfB[(((c*8+n)*4+s)*64+L)*8+e] = FMc[k][i], k=s*32+((L>>4)&3)*8+e, i=n*16+(L&15)
__global__ __launch_bounds__(128)
void pack_pre(const float* __restrict__ fm, short* __restrict__ bfB)
{
    const int idx = blockIdx.x * 128 + threadIdx.x;   // 16384 = 4c x 128k x 32 i4
    const int c  = idx >> 12;
    const int k  = (idx >> 5) & 127;
    const int i0 = (idx & 31) * 4;

    float4 v = *reinterpret_cast<const float4*>(fm + c * NA * NA + k * NA + i0);
    if (c >= 2) {
        v.x = (v.x > 15.0f) ? v.x : log1pf(__expf(v.x));
        v.y = (v.y > 15.0f) ? v.y : log1pf(__expf(v.y));
        v.z = (v.z > 15.0f) ? v.z : log1pf(__expf(v.z));
        v.w = (v.w > 15.0f) ? v.w : log1pf(__expf(v.w));
    }
    const int s  = k >> 5;
    const int e  = k & 7;
    const int Lk = ((k >> 3) & 3) * 16;
    const float vv[4] = {v.x, v.y, v.z, v.w};
#pragma unroll
    for (int d = 0; d < 4; ++d) {
        const int i = i0 + d;
        const int n = i >> 4;
        const int L = Lk + (i & 15);
        bfB[(((c * 8 + n) * 4 + s) * 64 + L) * 8 + e] = f2bf(vv[d]);
    }
}

// ---------- main kernel ----------
__global__ __launch_bounds__(THREADS)
void cnp_mfma(const short* __restrict__ bfB,   // [4][8][4][64][8] bf16
              const float* __restrict__ grid,  // [NA*NA][2]
              const float* __restrict__ xt,    // [T][2]
              const float* __restrict__ lsp,   // [1]
              float* __restrict__ out,         // means [T][2] then sigmas [T][2]
              int n_target)
{
    __shared__ __attribute__((aligned(16))) float Kx[TT * NA];      // 8 KB
    __shared__ __attribute__((aligned(16))) float Ky32[TT * NA];    // 8 KB
    __shared__ __attribute__((aligned(16))) short kyA[4 * 64 * 8];  // 4 KB
    __shared__ float psx[TT], psy[TT];
    __shared__ float red[4][2][TT];

    const int tid   = threadIdx.x;
    const int wid   = tid >> 6;
    const int c     = wid & 3;        // channel
    const int nh    = wid >> 2;       // n-half
    const int lane  = tid & 63;
    const int tbase = blockIdx.x * (TT * TILES);

    // ---- B-frag prefetch: once per block, reused by all tiles ----
    const short8* bbase = reinterpret_cast<const short8*>(bfB)
                        + c * 2048 + nh * 1024 + lane;
    const short8 b00 = bbase[0],         b01 = bbase[64],
                 b02 = bbase[128],       b03 = bbase[192];
    const short8 b10 = bbase[256],       b11 = bbase[256 + 64],
                 b12 = bbase[256 + 128], b13 = bbase[256 + 192];
    const short8 b20 = bbase[512],       b21 = bbase[512 + 64],
                 b22 = bbase[512 + 128], b23 = bbase[512 + 192];
    const short8 b30 = bbase[768],       b31 = bbase[768 + 64],
                 b32 = bbase[768 + 128], b33 = bbase[768 + 192];

    const float l      = lsp[0];
    const float inv2l2 = 0.5f / (l * l);

    const int icol = lane & 15;
    const int tb   = (lane >> 4) * 4;

    for (int tt = 0; tt < TILES; ++tt) {
        const int t0 = tbase + tt * TT;

        // ---- phase 0: exps -> LDS (Kx fp32, Ky fp32 + bf16 A-frag) ----
        // grid[g] = (ax[g>>7], ax[g&127])  =>  ax[j] = grid[j*2+1]
#pragma unroll
        for (int s = 0; s < 4; ++s) {
            const int k = s * THREADS + tid;   // 0..2047
            const int t = k >> 7;
            const int j = k & 127;
            int tg = t0 + t; if (tg >= n_target) tg = n_target - 1;
            const float ax = grid[j * 2 + 1];
            const float dx = xt[tg * 2 + 0] - ax;
            const float dy = xt[tg * 2 + 1] - ax;
            const float kxv = __expf(-dx * dx * inv2l2);
            const float kyv = __expf(-dy * dy * inv2l2);
            Kx[t * NA + j]   = kxv;
            Ky32[t * NA + j] = kyv;
            const int ss = j >> 5, g = (j & 31) >> 3, e = j & 7;
            kyA[((ss * 64) + g * 16 + (t & 15)) * 8 + e] = f2bf(kyv);
        }
        __syncthreads();

        // ---- Sx/Sy: shallow reduce, 32 groups (t x axis) x 16 lanes ----
        {
            const int grp  = tid >> 4;        // 0..31
            const int l16  = tid & 15;
            const int t    = grp >> 1;
            const int axis = grp & 1;
            const float* kb = axis ? Ky32 : Kx;
            const float4 q0 = *reinterpret_cast<const float4*>(&kb[t * NA + l16 * 8]);
            const float4 q1 = *reinterpret_cast<const float4*>(&kb[t * NA + l16 * 8 + 4]);
            float u = ((q0.x + q0.y) + (q0.z + q0.w)) + ((q1.x + q1.y) + (q1.z + q1.w));
            u += __shfl_xor(u, 1); u += __shfl_xor(u, 2);
            u += __shfl_xor(u, 4); u += __shfl_xor(u, 8);
            if (l16 == 0) { if (axis) psy[t] = u; else psx[t] = u; }
        }

        // ---- A-frags ----
        const short8* kap = reinterpret_cast<const short8*>(kyA);
        const short8 a0 = kap[0 * 64 + lane];
        const short8 a1 = kap[1 * 64 + lane];
        const short8 a2 = kap[2 * 64 + lane];
        const short8 a3 = kap[3 * 64 + lane];

        // ---- MFMA + stage-2 dot ----
        f32x4 p = {0.f, 0.f, 0.f, 0.f};
#define NTILE(NN, B0, B1, B2, B3)                                              \
        {                                                                      \
            f32x4 acc = {0.f, 0.f, 0.f, 0.f};                                  \
            acc = __builtin_amdgcn_mfma_f32_16x16x32_bf16(a0, B0, acc, 0, 0, 0); \
            acc = __builtin_amdgcn_mfma_f32_16x16x32_bf16(a1, B1, acc, 0, 0, 0); \
            acc = __builtin_amdgcn_mfma_f32_16x16x32_bf16(a2, B2, acc, 0, 0, 0); \
            acc = __builtin_amdgcn_mfma_f32_16x16x32_bf16(a3, B3, acc, 0, 0, 0); \
            const int i = (nh * 4 + (NN)) * 16 + icol;                         \
            p.x = fmaf(Kx[(tb + 0) * NA + i], acc.x, p.x);                     \
            p.y = fmaf(Kx[(tb + 1) * NA + i], acc.y, p.y);                     \
            p.z = fmaf(Kx[(tb + 2) * NA + i], acc.z, p.z);                     \
            p.w = fmaf(Kx[(tb + 3) * NA + i], acc.w, p.w);                     \
        }
        NTILE(0, b00, b01, b02, b03)
        NTILE(1, b10, b11, b12, b13)
        NTILE(2, b20, b21, b22, b23)
        NTILE(3, b30, b31, b32, b33)
#undef NTILE

        // ---- reduce numer over the 16 i-lanes (strides 1,2,4,8) ----
#pragma unroll
        for (int st = 1; st <= 8; st <<= 1) {
            p.x += __shfl_xor(p.x, st);
            p.y += __shfl_xor(p.y, st);
            p.z += __shfl_xor(p.z, st);
            p.w += __shfl_xor(p.w, st);
        }
        if (icol == 0) {
            red[c][nh][tb + 0] = p.x;
            red[c][nh][tb + 1] = p.y;
            red[c][nh][tb + 2] = p.z;
            red[c][nh][tb + 3] = p.w;
        }
        __syncthreads();

        // ---- epilogue: combine n-halves, normalize, write (64 outputs) ----
        if (tid < 4 * TT) {
            const int t  = tid & (TT - 1);
            const int cc = tid >> 4;            // requires TT == 16
            const int tg = t0 + t;
            if (tg < n_target) {
                const float numer = red[cc][0][t] + red[cc][1][t];
                const float val = numer / (psx[t] * psy[t]);
                if (cc < 2) out[tg * 2 + cc] = val;                      // means
                else        out[n_target * 2 + tg * 2 + (cc - 2)] = val; // sigmas
            }
        }
    }
}

extern "C" void kernel_launch(void* const* d_in, const int* in_sizes, int n_in,
                              void* d_out, int out_size, void* d_ws, size_t ws_size,
                              hipStream_t stream) {
    const float* fm   = (const float*)d_in[0];
    const float* grid = (const float*)d_in[1];
    const float* xt   = (const float*)d_in[2];
    const float* lsp  = (const float*)d_in[3];
    float* out = (float*)d_out;
    short* bfB = (short*)d_ws;                     // 4*8*4*64*8 bf16 = 128 KB

    const int n_target = in_sizes[2] / 2;          // 8192

    hipLaunchKernelGGL(pack_pre, dim3(128), dim3(128), 0, stream, fm, bfB);

    const int blocks = (n_target + TT * TILES - 1) / (TT * TILES);   // 256
    hipLaunchKernelGGL(cnp_mfma, dim3(blocks), dim3(THREADS), 0, stream,
                       bfB, grid, xt, lsp, out, n_target);
}